// Round 4
// baseline (5231.490 us; speedup 1.0000x reference)
//
#include <hip/hip_runtime.h>

// Liquid NN: BATCH=64, SEQ=256, IN=512, HID=1024, 2 layers, tau=0.5.
// h0(t) = h0 + a0*2*(tanh(x_t@W0^T + b0 + h0@U0^T) - h0)
// h1(t) = h1 + a1*2*(tanh(h0(t)@W1^T + b1 + h1@U1^T) - h1)
// Output: h1(255) as f32 (64,1024).
//
// R8: THREE-ROLE pipeline, 48 worker WGs on ONE elected XCD (2 WGs/CU:
// 64KB LDS -> 2/CU of 160KB; 256 VGPR cap -> 8 waves/CU; launch_bounds(256,2);
// 1024 blocks so each XCD fills ~64 resident before election needs 48).
//   role0 (slices 0-15): h0(s) = EMA(tanh(wx[s] + U0*h0(s-1))) -> h0 ring
//   roleW (slices 0-15): y1(t) = W1*h0(t)                      -> y1 ring (f16)
//   role1 (slices 0-15): h1(t) = EMA(tanh(y1(t)+b1+U1*h1(t-1)))-> h1 ring, out
// EVERY role's iteration is ONE slab + ONE reduce + ONE epilogue (R6's role1
// had two slabs serial = the period-setter; R7 put W1 on role0 and lengthened
// role0 instead - max(role periods) unchanged, L2 blew up).
// Rings are DEPTH 4 (3 rings = 1.5MB << 4MB XCD L2; R7's 8-deep 3-ring set +
// doubled LDS thrashed: WRITE 101MB, FETCH 42MB).
//
// Flag algebra (depth-4 rings, all slab reads behind full 16-word poll + bar):
//   role0(s): flag0>=s (peers' h0(s-1)); flagW>=s-3 (h0 slot s&3 consumed)
//   roleW(t): flag0>=t+1 (h0(t) visible); flag1>=t-3 (y1 slot t&3 consumed)
//   role1(t): flagW>=t+1 (y1(t) visible); flag1>=t (peers' h1(t-1) + h1 ring)
// Sync primitives are R4-validated AGENT atomics only; poll ALWAYS followed by
// __syncthreads before slab reads (R5 lesson); l1_inv before ring reads;
// producer stores drained by __syncthreads (vmcnt0) before the flag store.
// R6 keepers: NT wx loads, fast exp-based tanh, XOR-swizzled LDS reduce.

typedef _Float16 f16;
typedef _Float16 f16x8 __attribute__((ext_vector_type(8)));
typedef float    f32x4 __attribute__((ext_vector_type(4)));

#define B_  64
#define S_  256
#define IN_ 512
#define H_  1024

static constexpr size_t OFF_WX  = 0;         // S*B*H f16 = 33554432
static constexpr size_t OFF_H0R = 33554432;  // 4*B*H f16 = 524288
static constexpr size_t OFF_H1R = 34078720;  // 4*B*H f16 = 524288
static constexpr size_t OFF_Y1R = 34603008;  // 4*B*H f16 = 524288
static constexpr size_t OFF_FLG = 35127296;  // flags
// flg ints: flag0w[16]@0, flagWw[16]@16, flag1w[16]@32,
//           cnt[8]@48, chosen@56, ticket@57

#define AGENT __HIP_MEMORY_SCOPE_AGENT

// ---------------- kernel: Wx = x @ W0^T + b0 (f32 in, f16 out) ----------------
__global__ __launch_bounds__(256) void k_wx(const float* __restrict__ x,
                                            const float* __restrict__ W0,
                                            const float* __restrict__ b0,
                                            f16* __restrict__ wx) {
  __shared__ uint4 xs[4096];  // 64 rows x 64 8-half chunks, chunk' = kc ^ (row&7)
  const int tid = threadIdx.x;
  const int w = tid >> 6, lane = tid & 63;
  const int q = lane >> 4, l15 = lane & 15;
  const int cslice = blockIdx.x & 15;
  const int rblock = blockIdx.x >> 4;  // 0..31
  const int c = cslice * 64 + w * 16 + l15;

  f16x8 Bf[16];  // B[k][n] = W0[c][k], lane holds k = kf*32 + q*8 + j
#pragma unroll
  for (int kf = 0; kf < 16; ++kf) {
    const float* p = W0 + (size_t)c * IN_ + kf * 32 + q * 8;
    f16x8 v;
#pragma unroll
    for (int j = 0; j < 8; ++j) v[j] = (f16)p[j];
    Bf[kf] = v;
  }
  const float bias = b0[c];

  for (int rt = 0; rt < 8; ++rt) {
    const int row0 = rblock * 512 + rt * 64;
    __syncthreads();
#pragma unroll
    for (int it = 0; it < 16; ++it) {
      int g = it * 256 + tid;
      int r = g >> 6, kc = g & 63;
      const float* xp = x + (size_t)(row0 + r) * IN_ + kc * 8;
      float4 v0 = *(const float4*)xp;
      float4 v1 = *(const float4*)(xp + 4);
      f16x8 h;
      h[0] = (f16)v0.x; h[1] = (f16)v0.y; h[2] = (f16)v0.z; h[3] = (f16)v0.w;
      h[4] = (f16)v1.x; h[5] = (f16)v1.y; h[6] = (f16)v1.z; h[7] = (f16)v1.w;
      xs[r * 64 + (kc ^ (r & 7))] = *(uint4*)&h;
    }
    __syncthreads();
    f32x4 acc[4] = {};
#pragma unroll
    for (int mt = 0; mt < 4; ++mt) {
      const int r = mt * 16 + l15;
#pragma unroll
      for (int kf = 0; kf < 16; ++kf) {
        uint4 av = xs[r * 64 + ((kf * 4 + q) ^ (r & 7))];
        f16x8 a = *(f16x8*)&av;
        acc[mt] = __builtin_amdgcn_mfma_f32_16x16x32_f16(a, Bf[kf], acc[mt], 0, 0, 0);
      }
    }
#pragma unroll
    for (int mt = 0; mt < 4; ++mt) {
#pragma unroll
      for (int r = 0; r < 4; ++r) {
        int rowg = row0 + mt * 16 + q * 4 + r;  // = b*256 + t
        int b = rowg >> 8, t = rowg & 255;
        wx[((size_t)t * B_ + b) * H_ + c] = (f16)(acc[mt][r] + bias);
      }
    }
  }
}

// ---------------- persistent recurrent kernel ----------------
__device__ __forceinline__ void l1_inv() {
  asm volatile("buffer_inv" ::: "memory");  // L1-only: elected-XCD L2 is coherence pt
}

// whole-wave vector poll: lanes 0-15 wait f[lane] >= tgt (one 64B line / round trip)
__device__ __forceinline__ void pollw(const int* f, int tgt, int lane) {
  bool pend = (lane < 16) && (tgt > 0);
  const int* p = f + (lane & 15);
  while (__ballot(pend)) {
    if (pend && __hip_atomic_load((int*)p, __ATOMIC_RELAXED, AGENT) >= tgt)
      pend = false;
  }
}

// fast tanh: t = e^{-2|x|} in (0,1], tanh = sign(x)*(1-t)/(1+t). ~1e-7 abs err.
__device__ __forceinline__ float fast_tanh(float x) {
  float t = __expf(-2.0f * fabsf(x));
  float r = (1.0f - t) / (1.0f + t);
  return copysignf(r, x);
}

// one wave: 64-batch x 64-col x 256-K slab, software-pipelined A loads.
__device__ __forceinline__ void gemm_slab(const f16* __restrict__ A, int kbase,
                                          int l15, int q,
                                          const f16x8 (&Bf)[4][8], f32x4 (&acc)[4][4]) {
  f16x8 cur[8], nxt[8];
  const f16* ar0 = A + (size_t)l15 * H_ + kbase + q * 8;
#pragma unroll
  for (int kf = 0; kf < 8; ++kf) cur[kf] = *(const f16x8*)(ar0 + kf * 32);
#pragma unroll
  for (int mt = 0; mt < 4; ++mt) {
    if (mt < 3) {
      const f16* ar = A + (size_t)((mt + 1) * 16 + l15) * H_ + kbase + q * 8;
#pragma unroll
      for (int kf = 0; kf < 8; ++kf) nxt[kf] = *(const f16x8*)(ar + kf * 32);
    }
#pragma unroll
    for (int nt = 0; nt < 4; ++nt)
#pragma unroll
      for (int kf = 0; kf < 8; ++kf)
        acc[mt][nt] = __builtin_amdgcn_mfma_f32_16x16x32_f16(cur[kf], Bf[nt][kf],
                                                             acc[mt][nt], 0, 0, 0);
#pragma unroll
    for (int kf = 0; kf < 8; ++kf) cur[kf] = nxt[kf];
  }
}

__global__ __launch_bounds__(256, 2) void k_persist(
    const float* __restrict__ U0, const float* __restrict__ W1,
    const float* __restrict__ U1, const float* __restrict__ alpha0,
    const float* __restrict__ alpha1, const float* __restrict__ b1,
    const f16* __restrict__ wx, f16* h0r, f16* h1r, f16* y1r, int* flg,
    float* out) {
  // red[ks][i][col]: D[m][n] of K-slice ks, m=(i>>4)*16+(col>>4)*4+(i&3),
  // n=((i>>2)&3)*16+(col&15), XOR-swizzled at col' = col ^ ((i&3)<<2).
  // aligned(16): epilogue does b128 LDS reads. 64 KiB -> 2 WGs/CU.
  __shared__ __attribute__((aligned(16))) float red[4][64][64];
  const int tid = threadIdx.x;
  const int w = tid >> 6, lane = tid & 63;
  const int q = lane >> 4, l15 = lane & 15;

  int* flag0w = flg;        // word j = steps completed by role0 WG j
  int* flagWw = flg + 16;   // word j = steps completed by roleW WG j
  int* flag1w = flg + 32;   // word j = steps completed by role1 WG j
  int* cnt    = flg + 48;
  int* chosen = flg + 56;
  int* ticket = flg + 57;

  // ---- elect one XCD; 48 workers there; everyone else exits ----
  const int xcc = (int)__builtin_amdgcn_s_getreg(6164) & 7;  // HW_REG_XCC_ID
  int* sh = (int*)&red[0][0][0];
  if (tid == 0) {
    __hip_atomic_fetch_add(cnt + xcc, 1, __ATOMIC_RELAXED, AGENT);
    if (blockIdx.x == 0) {
      int sel = -1;
      while (sel < 0) {
        for (int i = 0; i < 8; ++i)
          if (__hip_atomic_load(cnt + i, __ATOMIC_RELAXED, AGENT) >= 48) { sel = i; break; }
        if (sel < 0) __builtin_amdgcn_s_sleep(1);
      }
      __hip_atomic_fetch_add(chosen, sel + 1, __ATOMIC_RELAXED, AGENT);
    }
    int ch;
    while ((ch = __hip_atomic_load(chosen, __ATOMIC_RELAXED, AGENT)) == 0)
      __builtin_amdgcn_s_sleep(1);
    int my = -1;
    if (xcc == ch - 1) my = __hip_atomic_fetch_add(ticket, 1, __ATOMIC_RELAXED, AGENT);
    sh[0] = my;
  }
  __syncthreads();
  const int myid = sh[0];
  __syncthreads();
  if (myid < 0 || myid >= 48) return;
  const int role = myid >> 4, slice = myid & 15;  // role: 0=h0, 1=W1*h0, 2=h1
  const int c0 = slice * 64;
  const int kbase = w * 256;

  // ---- ONE weight slice per role into registers: B[k][n] = Wm[c][k] ----
  const float* Wsel = (role == 0) ? U0 : (role == 1) ? W1 : U1;
  f16x8 Bf[4][8];
#pragma unroll
  for (int nt = 0; nt < 4; ++nt)
#pragma unroll
    for (int kf = 0; kf < 8; ++kf) {
      const float* p = Wsel + (size_t)(c0 + nt * 16 + l15) * H_ + kbase + kf * 32 + q * 8;
      f16x8 v;
#pragma unroll
      for (int j = 0; j < 8; ++j) v[j] = (f16)p[j];
      Bf[nt][kf] = v;
    }

  // ---- epilogue ownership: thread owns batch row bown, cols cbase..cbase+15 ----
  const int bown = w * 16 + (lane & 15);
  const int gq   = lane >> 4;
  const int iidx = w * 16 + gq * 4 + (lane & 3);  // fixed LDS row
  const int lsb  = ((lane >> 2) & 3) * 16;        // fixed logical col base
  const int swz  = (lane & 3) << 2;               // read-side XOR (row&3 == lane&3)
  const int cbase = c0 + gq * 16;

  f16x8 cfh[2], bsh[2];  // packed alpha*2 (roles 0,2) and b1 (role 2)
  if (role != 1) {
    const float* ap = ((role == 0) ? alpha0 : alpha1) + cbase;
    const float* bp = b1 + cbase;
    f16x8 t0, t1, u0, u1;
#pragma unroll
    for (int j = 0; j < 8; ++j) {
      t0[j] = (f16)(ap[j] * 2.0f);
      t1[j] = (f16)(ap[8 + j] * 2.0f);
      u0[j] = (f16)bp[j];
      u1[j] = (f16)bp[8 + j];
    }
    cfh[0] = t0; cfh[1] = t1; bsh[0] = u0; bsh[1] = u1;
  }

  float hst[16];
#pragma unroll
  for (int i = 0; i < 16; ++i) hst[i] = 0.f;

  if (role == 0) {
    // ---- role0: h0(s) = EMA(tanh(wx[s] + U0*h0(s-1))) ----
    for (int s = 0; s < 256; ++s) {
      const f16* wp = wx + ((size_t)s * B_ + bown) * H_ + cbase;
      f16x8 wxa = __builtin_nontemporal_load((const f16x8*)wp);
      f16x8 wxb = __builtin_nontemporal_load((const f16x8*)(wp + 8));
      f32x4 acc[4][4] = {};
      if (s > 0) {
        if (w == 0) pollw(flag0w, s, lane);      // peers' h0(s-1)
        if (w == 1) pollw(flagWw, s - 3, lane);  // h0 slot s&3 consumed by roleW
        __syncthreads();
        l1_inv();
        gemm_slab(h0r + (size_t)((s - 1) & 3) * B_ * H_, kbase, l15, q, Bf, acc);
      }
#pragma unroll
      for (int mt = 0; mt < 4; ++mt)
#pragma unroll
        for (int nt = 0; nt < 4; ++nt)
#pragma unroll
          for (int r = 0; r < 4; ++r)
            red[w][mt * 16 + nt * 4 + r][lane ^ (r << 2)] = acc[mt][nt][r];
      __syncthreads();
      float vs[16];
#pragma unroll
      for (int ks = 0; ks < 4; ++ks)
#pragma unroll
        for (int ch = 0; ch < 4; ++ch) {
          f32x4 v = *(const f32x4*)&red[ks][iidx][lsb + ((ch << 2) ^ swz)];
          if (ks == 0) {
            vs[ch*4+0] = v[0]; vs[ch*4+1] = v[1]; vs[ch*4+2] = v[2]; vs[ch*4+3] = v[3];
          } else {
            vs[ch*4+0] += v[0]; vs[ch*4+1] += v[1]; vs[ch*4+2] += v[2]; vs[ch*4+3] += v[3];
          }
        }
      f16* hw = h0r + (size_t)(s & 3) * B_ * H_ + (size_t)bown * H_ + cbase;
      f16x8 o0, o1;
#pragma unroll
      for (int j = 0; j < 16; ++j) {
        float wxv = (float)((j < 8) ? wxa[j] : wxb[j - 8]);
        float cf  = (float)((j < 8) ? cfh[0][j] : cfh[1][j - 8]);
        float th = fast_tanh(vs[j] + wxv);
        float h = hst[j];
        h = h + cf * (th - h);
        hst[j] = h;
        if (j < 8) o0[j] = (f16)h; else o1[j - 8] = (f16)h;
      }
      *(f16x8*)hw = o0;
      *(f16x8*)(hw + 8) = o1;
      __syncthreads();  // vmcnt(0) per wave: h0 stores in L2 before flag
      if (tid == 0)
        __hip_atomic_store(flag0w + slice, s + 1, __ATOMIC_RELAXED, AGENT);
    }
  } else if (role == 1) {
    // ---- roleW: y1(t) = W1*h0(t) -> f16 y-ring ----
    for (int t = 0; t < 256; ++t) {
      if (w == 0) pollw(flag0w, t + 1, lane);    // h0(t) visible
      if (w == 1) pollw(flag1w, t - 3, lane);    // y1 slot t&3 consumed by role1
      __syncthreads();
      l1_inv();
      f32x4 acc[4][4] = {};
      gemm_slab(h0r + (size_t)(t & 3) * B_ * H_, kbase, l15, q, Bf, acc);
#pragma unroll
      for (int mt = 0; mt < 4; ++mt)
#pragma unroll
        for (int nt = 0; nt < 4; ++nt)
#pragma unroll
          for (int r = 0; r < 4; ++r)
            red[w][mt * 16 + nt * 4 + r][lane ^ (r << 2)] = acc[mt][nt][r];
      __syncthreads();
      float vs[16];
#pragma unroll
      for (int ks = 0; ks < 4; ++ks)
#pragma unroll
        for (int ch = 0; ch < 4; ++ch) {
          f32x4 v = *(const f32x4*)&red[ks][iidx][lsb + ((ch << 2) ^ swz)];
          if (ks == 0) {
            vs[ch*4+0] = v[0]; vs[ch*4+1] = v[1]; vs[ch*4+2] = v[2]; vs[ch*4+3] = v[3];
          } else {
            vs[ch*4+0] += v[0]; vs[ch*4+1] += v[1]; vs[ch*4+2] += v[2]; vs[ch*4+3] += v[3];
          }
        }
      f16* yw = y1r + (size_t)(t & 3) * B_ * H_ + (size_t)bown * H_ + cbase;
      f16x8 y0, y1;
#pragma unroll
      for (int j = 0; j < 16; ++j) {
        if (j < 8) y0[j] = (f16)vs[j]; else y1[j - 8] = (f16)vs[j];
      }
      *(f16x8*)yw = y0;
      *(f16x8*)(yw + 8) = y1;
      __syncthreads();  // vmcnt(0) per wave: y1 stores in L2 before flag
      if (tid == 0)
        __hip_atomic_store(flagWw + slice, t + 1, __ATOMIC_RELAXED, AGENT);
    }
  } else {
    // ---- role1: h1(t) = EMA(tanh(y1(t) + b1 + U1*h1(t-1))) ----
    for (int t = 0; t < 256; ++t) {
      if (w == 0) pollw(flagWw, t + 1, lane);    // y1(t) visible
      if (w == 1) pollw(flag1w, t, lane);        // peers' h1(t-1) + h1 ring
      __syncthreads();
      l1_inv();
      // y1(t) loads issued BEFORE the slab: older in vmcnt FIFO -> hidden.
      const f16* yp = y1r + (size_t)(t & 3) * B_ * H_ + (size_t)bown * H_ + cbase;
      f16x8 ya = *(const f16x8*)yp;
      f16x8 yb = *(const f16x8*)(yp + 8);
      f32x4 acc[4][4] = {};
      if (t > 0)
        gemm_slab(h1r + (size_t)((t - 1) & 3) * B_ * H_, kbase, l15, q, Bf, acc);
#pragma unroll
      for (int mt = 0; mt < 4; ++mt)
#pragma unroll
        for (int nt = 0; nt < 4; ++nt)
#pragma unroll
          for (int r = 0; r < 4; ++r)
            red[w][mt * 16 + nt * 4 + r][lane ^ (r << 2)] = acc[mt][nt][r];
      __syncthreads();
      float vs[16];
#pragma unroll
      for (int ks = 0; ks < 4; ++ks)
#pragma unroll
        for (int ch = 0; ch < 4; ++ch) {
          f32x4 v = *(const f32x4*)&red[ks][iidx][lsb + ((ch << 2) ^ swz)];
          if (ks == 0) {
            vs[ch*4+0] = v[0]; vs[ch*4+1] = v[1]; vs[ch*4+2] = v[2]; vs[ch*4+3] = v[3];
          } else {
            vs[ch*4+0] += v[0]; vs[ch*4+1] += v[1]; vs[ch*4+2] += v[2]; vs[ch*4+3] += v[3];
          }
        }
      f16* hw = h1r + (size_t)(t & 3) * B_ * H_ + (size_t)bown * H_ + cbase;
      f16x8 o0, o1;
#pragma unroll
      for (int j = 0; j < 16; ++j) {
        float yv = (float)((j < 8) ? ya[j] : yb[j - 8]);
        float bs = (float)((j < 8) ? bsh[0][j] : bsh[1][j - 8]);
        float cf = (float)((j < 8) ? cfh[0][j] : cfh[1][j - 8]);
        float th = fast_tanh(vs[j] + yv + bs);
        float h = hst[j];
        h = h + cf * (th - h);
        hst[j] = h;
        if (j < 8) o0[j] = (f16)h; else o1[j - 8] = (f16)h;
      }
      *(f16x8*)hw = o0;
      *(f16x8*)(hw + 8) = o1;
      if (t == 255) {
        float* op = out + (size_t)bown * H_ + cbase;
#pragma unroll
        for (int ch = 0; ch < 4; ++ch) {
          float4 vv;
          vv.x = hst[ch*4+0]; vv.y = hst[ch*4+1]; vv.z = hst[ch*4+2]; vv.w = hst[ch*4+3];
          *(float4*)(op + ch * 4) = vv;
        }
      }
      __syncthreads();
      if (tid == 0)
        __hip_atomic_store(flag1w + slice, t + 1, __ATOMIC_RELAXED, AGENT);
    }
  }
}

// Swizzle identity: writer lane L stores logical col L at physical col
// L ^ ((i&3)<<2). Reader (row iidx, iidx&3 == lane&3) reads physical
// lsb + ((ch<<2) ^ ((lane&3)<<2)) + nn, which un-XORs to logical
// lsb + ch*4 + nn. Writes are lane-permutations (conflict-free); b128 reads
// spread across all 32 banks (conflict-free).

extern "C" void kernel_launch(void* const* d_in, const int* in_sizes, int n_in,
                              void* d_out, int out_size, void* d_ws, size_t ws_size,
                              hipStream_t stream) {
  const float* x  = (const float*)d_in[0];
  const float* W0 = (const float*)d_in[1];
  const float* U0 = (const float*)d_in[2];
  const float* b0 = (const float*)d_in[3];
  const float* a0 = (const float*)d_in[4];
  const float* W1 = (const float*)d_in[5];
  const float* U1 = (const float*)d_in[6];
  const float* b1 = (const float*)d_in[7];
  const float* a1 = (const float*)d_in[8];
  char* ws = (char*)d_ws;
  f16*   wx  = (f16*)(ws + OFF_WX);
  f16*   h0r = (f16*)(ws + OFF_H0R);
  f16*   h1r = (f16*)(ws + OFF_H1R);
  f16*   y1r = (f16*)(ws + OFF_Y1R);
  int*   flg = (int*)(ws + OFF_FLG);
  float* out = (float*)d_out;

  hipMemsetAsync(flg, 0, 8192, stream);            // flags/election start at 0
  k_wx<<<512, 256, 0, stream>>>(x, W0, b0, wx);    // parallel Wx GEMM

  // 1024 blocks: 2 WGs/CU resident (64KB LDS, 256 VGPR cap) -> ~64/XCD wait on
  // `chosen`, so the elected XCD can seat 48 workers; everyone else exits.
  k_persist<<<1024, 256, 0, stream>>>(U0, W1, U1, a0, a1, b1, wx, h0r, h1r, y1r,
                                      flg, out);
}

// Round 5
// 2918.354 us; speedup vs baseline: 1.7926x; 1.7926x over previous
//
#include <hip/hip_runtime.h>

// Liquid NN: BATCH=64, SEQ=256, IN=512, HID=1024, 2 layers, tau=0.5.
// h0(t) = h0 + a0*2*(tanh(x_t@W0^T + b0 + h0@U0^T) - h0)
// h1(t) = h1 + a1*2*(tanh(h0(t)@W1^T + b1 + h1@U1^T) - h1)
// Output: h1(255) as f32 (64,1024).
//
// R9 = R6 structure (best passing: 2805us) with the SYNC SUBSTRATE swapped to
// per-step COMPLETION COUNTERS:
//   cnt0[s] = #role0 WGs that finished step s; cnt1[t] = #role1 WGs finished t.
//   "all 16 peer flags >= v" == "cnt[v-1] == 16" (identical algebra to R6).
// WHY: R6 polls were 64 hot-spinning waves x 16 PER-LANE atomic loads on ONE
// 64B line (atomics don't coalesce -> ~3.4 TCC tx/cyc demand on one channel
// vs ~0.2 supply). The saturated channel queue put ~us-scale latency on every
// flag store AND poll check - the invariant ~11us step floor across R4/R6/R7.
// Now: consumers poll ONE word with ONE lane (+s_sleep backoff); producers do
// one fetch_add per WG per step. ~50x less traffic on the hot line.
// R8 lesson: launch_bounds(256,2) halves unified VGPR to 128 -> 970MB spill
// traffic. This family needs 1 WG/CU (256 VGPR + AGPR). Stay at 32 WGs.
//
// Roles (16 WGs each, one elected XCD, depth-8 f16 rings):
//   role0: h0(s) = EMA(tanh(wx[s] + U0*h0(s-1)))
//   role1: h1(t) = EMA(tanh(b1 + W1*h0(t) + U1*h1(t-1)))  [two-phase polls]
// Protocol (counters): role0 step s: cnt0[s-1]==16, cnt1[s-8]==16 (ring).
//   role1 step t: phase A cnt0[t]==16 (h0(t) ready); phase B cnt1[t-1]==16
//   (peers' h1(t-1) + h1 ring slot free). Poll ALWAYS followed by
//   __syncthreads before slab reads (R5 lesson); l1_inv before ring reads;
//   producer stores drained by __syncthreads (vmcnt0) before the publish RMW.
// R6 keepers: NT wx loads, fast exp-based tanh, XOR-swizzled LDS reduce.

typedef _Float16 f16;
typedef _Float16 f16x8 __attribute__((ext_vector_type(8)));
typedef float    f32x4 __attribute__((ext_vector_type(4)));

#define B_  64
#define S_  256
#define IN_ 512
#define H_  1024

static constexpr size_t OFF_WX  = 0;         // S*B*H f16 = 33554432
static constexpr size_t OFF_H0R = 33554432;  // 8*B*H f16 = 1048576
static constexpr size_t OFF_H1R = 34603008;  // 8*B*H f16 = 1048576
static constexpr size_t OFF_FLG = 35651584;  // sync area (memset 8192 B)
// flg ints: cnt0[257]@0, cnt1[257]@512, ecnt[8]@1024, chosen@1032, ticket@1033

#define AGENT __HIP_MEMORY_SCOPE_AGENT

// ---------------- kernel: Wx = x @ W0^T + b0 (f32 in, f16 out) ----------------
__global__ __launch_bounds__(256) void k_wx(const float* __restrict__ x,
                                            const float* __restrict__ W0,
                                            const float* __restrict__ b0,
                                            f16* __restrict__ wx) {
  __shared__ uint4 xs[4096];  // 64 rows x 64 8-half chunks, chunk' = kc ^ (row&7)
  const int tid = threadIdx.x;
  const int w = tid >> 6, lane = tid & 63;
  const int q = lane >> 4, l15 = lane & 15;
  const int cslice = blockIdx.x & 15;
  const int rblock = blockIdx.x >> 4;  // 0..31
  const int c = cslice * 64 + w * 16 + l15;

  f16x8 Bf[16];  // B[k][n] = W0[c][k], lane holds k = kf*32 + q*8 + j
#pragma unroll
  for (int kf = 0; kf < 16; ++kf) {
    const float* p = W0 + (size_t)c * IN_ + kf * 32 + q * 8;
    f16x8 v;
#pragma unroll
    for (int j = 0; j < 8; ++j) v[j] = (f16)p[j];
    Bf[kf] = v;
  }
  const float bias = b0[c];

  for (int rt = 0; rt < 8; ++rt) {
    const int row0 = rblock * 512 + rt * 64;
    __syncthreads();
#pragma unroll
    for (int it = 0; it < 16; ++it) {
      int g = it * 256 + tid;
      int r = g >> 6, kc = g & 63;
      const float* xp = x + (size_t)(row0 + r) * IN_ + kc * 8;
      float4 v0 = *(const float4*)xp;
      float4 v1 = *(const float4*)(xp + 4);
      f16x8 h;
      h[0] = (f16)v0.x; h[1] = (f16)v0.y; h[2] = (f16)v0.z; h[3] = (f16)v0.w;
      h[4] = (f16)v1.x; h[5] = (f16)v1.y; h[6] = (f16)v1.z; h[7] = (f16)v1.w;
      xs[r * 64 + (kc ^ (r & 7))] = *(uint4*)&h;
    }
    __syncthreads();
    f32x4 acc[4] = {};
#pragma unroll
    for (int mt = 0; mt < 4; ++mt) {
      const int r = mt * 16 + l15;
#pragma unroll
      for (int kf = 0; kf < 16; ++kf) {
        uint4 av = xs[r * 64 + ((kf * 4 + q) ^ (r & 7))];
        f16x8 a = *(f16x8*)&av;
        acc[mt] = __builtin_amdgcn_mfma_f32_16x16x32_f16(a, Bf[kf], acc[mt], 0, 0, 0);
      }
    }
#pragma unroll
    for (int mt = 0; mt < 4; ++mt) {
#pragma unroll
      for (int r = 0; r < 4; ++r) {
        int rowg = row0 + mt * 16 + q * 4 + r;  // = b*256 + t
        int b = rowg >> 8, t = rowg & 255;
        wx[((size_t)t * B_ + b) * H_ + c] = (f16)(acc[mt][r] + bias);
      }
    }
  }
}

// ---------------- persistent recurrent kernel ----------------
__device__ __forceinline__ void l1_inv() {
  asm volatile("buffer_inv" ::: "memory");  // L1-only: elected-XCD L2 is coherence pt
}

// counter poll: lane 0 waits cnt[idx] >= 16. ONE word, ONE transaction per
// wave-check, s_sleep backoff after the first (hot) check. idx<0 -> no-op.
__device__ __forceinline__ void pollc(const int* cn, int idx, int lane) {
  if (idx < 0) return;
  const int* p = cn + idx;
  bool pend = (lane == 0);
  if (pend && __hip_atomic_load((int*)p, __ATOMIC_RELAXED, AGENT) >= 16)
    pend = false;
  while (__ballot(pend)) {
    __builtin_amdgcn_s_sleep(2);
    if (pend && __hip_atomic_load((int*)p, __ATOMIC_RELAXED, AGENT) >= 16)
      pend = false;
  }
}

// fast tanh: t = e^{-2|x|} in (0,1], tanh = sign(x)*(1-t)/(1+t). ~1e-7 abs err.
__device__ __forceinline__ float fast_tanh(float x) {
  float t = __expf(-2.0f * fabsf(x));
  float r = (1.0f - t) / (1.0f + t);
  return copysignf(r, x);
}

// one wave: 64-batch x 64-col x 256-K slab, software-pipelined A loads.
__device__ __forceinline__ void gemm_slab(const f16* __restrict__ A, int kbase,
                                          int l15, int q,
                                          const f16x8 (&Bf)[4][8], f32x4 (&acc)[4][4]) {
  f16x8 cur[8], nxt[8];
  const f16* ar0 = A + (size_t)l15 * H_ + kbase + q * 8;
#pragma unroll
  for (int kf = 0; kf < 8; ++kf) cur[kf] = *(const f16x8*)(ar0 + kf * 32);
#pragma unroll
  for (int mt = 0; mt < 4; ++mt) {
    if (mt < 3) {
      const f16* ar = A + (size_t)((mt + 1) * 16 + l15) * H_ + kbase + q * 8;
#pragma unroll
      for (int kf = 0; kf < 8; ++kf) nxt[kf] = *(const f16x8*)(ar + kf * 32);
    }
#pragma unroll
    for (int nt = 0; nt < 4; ++nt)
#pragma unroll
      for (int kf = 0; kf < 8; ++kf)
        acc[mt][nt] = __builtin_amdgcn_mfma_f32_16x16x32_f16(cur[kf], Bf[nt][kf],
                                                             acc[mt][nt], 0, 0, 0);
#pragma unroll
    for (int kf = 0; kf < 8; ++kf) cur[kf] = nxt[kf];
  }
}

__global__ __launch_bounds__(256, 1) void k_persist(
    const float* __restrict__ U0, const float* __restrict__ W1,
    const float* __restrict__ U1, const float* __restrict__ alpha0,
    const float* __restrict__ alpha1, const float* __restrict__ b1,
    const f16* __restrict__ wx, f16* h0r, f16* h1r, int* flg, float* out) {
  // red[ks][i][col]: D[m][n] of K-slice ks, m=(i>>4)*16+(col>>4)*4+(i&3),
  // n=((i>>2)&3)*16+(col&15), stored XOR-swizzled at col' = col ^ ((i&3)<<2).
  // aligned(16): epilogue does b128 LDS reads (under-aligned b128 = fault).
  __shared__ __attribute__((aligned(16))) float red[4][64][64];  // exactly 64 KiB
  const int tid = threadIdx.x;
  const int w = tid >> 6, lane = tid & 63;
  const int q = lane >> 4, l15 = lane & 15;

  int* cnt0   = flg;         // cnt0[s] = #role0 WGs that finished step s
  int* cnt1   = flg + 512;   // cnt1[t] = #role1 WGs that finished step t
  int* ecnt   = flg + 1024;
  int* chosen = flg + 1032;
  int* ticket = flg + 1033;

  // ---- elect one XCD; 32 workers there; everyone else exits (R4-validated) ----
  const int xcc = (int)__builtin_amdgcn_s_getreg(6164) & 7;  // HW_REG_XCC_ID
  int* sh = (int*)&red[0][0][0];
  if (tid == 0) {
    __hip_atomic_fetch_add(ecnt + xcc, 1, __ATOMIC_RELAXED, AGENT);
    if (blockIdx.x == 0) {
      int sel = -1;
      while (sel < 0) {
        for (int i = 0; i < 8; ++i)
          if (__hip_atomic_load(ecnt + i, __ATOMIC_RELAXED, AGENT) >= 32) { sel = i; break; }
        if (sel < 0) __builtin_amdgcn_s_sleep(1);
      }
      __hip_atomic_fetch_add(chosen, sel + 1, __ATOMIC_RELAXED, AGENT);
    }
    int ch;
    while ((ch = __hip_atomic_load(chosen, __ATOMIC_RELAXED, AGENT)) == 0)
      __builtin_amdgcn_s_sleep(1);
    int my = -1;
    if (xcc == ch - 1) my = __hip_atomic_fetch_add(ticket, 1, __ATOMIC_RELAXED, AGENT);
    sh[0] = my;
  }
  __syncthreads();
  const int myid = sh[0];
  __syncthreads();
  if (myid < 0 || myid >= 32) return;
  const int role = myid >> 4, slice = myid & 15;
  const int c0 = slice * 64;
  const int kbase = w * 256;

  // ---- weight slices into registers: B[k][n] = Wm[c][k] ----
  f16x8 BfA[4][8];  // role0: U0 ; role1: W1
  f16x8 BfB[4][8];  // role1: U1
  {
    const float* WmA = (role == 0) ? U0 : W1;
#pragma unroll
    for (int nt = 0; nt < 4; ++nt)
#pragma unroll
      for (int kf = 0; kf < 8; ++kf) {
        const float* p = WmA + (size_t)(c0 + nt * 16 + l15) * H_ + kbase + kf * 32 + q * 8;
        f16x8 v;
#pragma unroll
        for (int j = 0; j < 8; ++j) v[j] = (f16)p[j];
        BfA[nt][kf] = v;
      }
    if (role == 1) {
#pragma unroll
      for (int nt = 0; nt < 4; ++nt)
#pragma unroll
        for (int kf = 0; kf < 8; ++kf) {
          const float* p = U1 + (size_t)(c0 + nt * 16 + l15) * H_ + kbase + kf * 32 + q * 8;
          f16x8 v;
#pragma unroll
          for (int j = 0; j < 8; ++j) v[j] = (f16)p[j];
          BfB[nt][kf] = v;
        }
    }
  }

  // ---- epilogue ownership: thread owns batch row bown, cols cbase..cbase+15 ----
  const int bown = w * 16 + (lane & 15);
  const int gq   = lane >> 4;
  const int iidx = w * 16 + gq * 4 + (lane & 3);  // fixed LDS row
  const int lsb  = ((lane >> 2) & 3) * 16;        // fixed logical col base
  const int swz  = (lane & 3) << 2;               // read-side XOR (row&3 == lane&3)
  const int cbase = c0 + gq * 16;

  f16x8 cfh[2], bsh[2];  // packed alpha*2 and bias for the 16 owned cols
  {
    const float* ap = ((role == 0) ? alpha0 : alpha1) + cbase;
    const float* bp = b1 + cbase;
    f16x8 t0, t1, u0, u1;
#pragma unroll
    for (int j = 0; j < 8; ++j) {
      t0[j] = (f16)(ap[j] * 2.0f);
      t1[j] = (f16)(ap[8 + j] * 2.0f);
      u0[j] = (f16)bp[j];
      u1[j] = (f16)bp[8 + j];
    }
    cfh[0] = t0; cfh[1] = t1; bsh[0] = u0; bsh[1] = u1;
  }

  float hst[16];
#pragma unroll
  for (int i = 0; i < 16; ++i) hst[i] = 0.f;

  if (role == 0) {
    for (int s = 0; s < 256; ++s) {
      // prefetch wx[s] for owned (b, cols): 2 x b128 NT loads (no L2 allocate ->
      // h-rings stay L2-resident), in flight during the poll
      const f16* wp = wx + ((size_t)s * B_ + bown) * H_ + cbase;
      f16x8 wxa = __builtin_nontemporal_load((const f16x8*)wp);
      f16x8 wxb = __builtin_nontemporal_load((const f16x8*)(wp + 8));
      f32x4 acc[4][4] = {};
      if (s > 0) {
        if (w == 0) pollc(cnt0, s - 1, lane);  // peers finished s-1
        if (w == 1) pollc(cnt1, s - 8, lane);  // ring slot s&7 free
        __syncthreads();
        l1_inv();
        gemm_slab(h0r + (size_t)((s - 1) & 7) * B_ * H_, kbase, l15, q, BfA, acc);
      }
#pragma unroll
      for (int mt = 0; mt < 4; ++mt)
#pragma unroll
        for (int nt = 0; nt < 4; ++nt)
#pragma unroll
          for (int r = 0; r < 4; ++r)
            red[w][mt * 16 + nt * 4 + r][lane ^ (r << 2)] = acc[mt][nt][r];
      __syncthreads();
      float vs[16];
#pragma unroll
      for (int ks = 0; ks < 4; ++ks)
#pragma unroll
        for (int ch = 0; ch < 4; ++ch) {
          f32x4 v = *(const f32x4*)&red[ks][iidx][lsb + ((ch << 2) ^ swz)];
          if (ks == 0) {
            vs[ch*4+0] = v[0]; vs[ch*4+1] = v[1]; vs[ch*4+2] = v[2]; vs[ch*4+3] = v[3];
          } else {
            vs[ch*4+0] += v[0]; vs[ch*4+1] += v[1]; vs[ch*4+2] += v[2]; vs[ch*4+3] += v[3];
          }
        }
      f16* hw = h0r + (size_t)(s & 7) * B_ * H_ + (size_t)bown * H_ + cbase;
      f16x8 o0, o1;
#pragma unroll
      for (int j = 0; j < 16; ++j) {
        float wxv = (float)((j < 8) ? wxa[j] : wxb[j - 8]);
        float cf  = (float)((j < 8) ? cfh[0][j] : cfh[1][j - 8]);
        float th = fast_tanh(vs[j] + wxv);
        float h = hst[j];
        h = h + cf * (th - h);
        hst[j] = h;
        if (j < 8) o0[j] = (f16)h; else o1[j - 8] = (f16)h;
      }
      *(f16x8*)hw = o0;
      *(f16x8*)(hw + 8) = o1;
      __syncthreads();  // vmcnt(0) per wave: h stores in shared L2 before publish
      if (tid == 0)
        __hip_atomic_fetch_add(cnt0 + s, 1, __ATOMIC_RELAXED, AGENT);
    }
  } else {
    for (int t = 0; t < 256; ++t) {
      f32x4 acc[4][4] = {};
      // phase A: W1*h0(t). h0 is ready up to 8 steps early (ring slack), so this
      // poll is normally instant and the slab comes OFF the serial chain.
      if (w == 0) pollc(cnt0, t, lane);        // h0(t) ready
      __syncthreads();
      l1_inv();
      gemm_slab(h0r + (size_t)(t & 7) * B_ * H_, kbase, l15, q, BfA, acc);  // W1*h0(t)
      if (t > 0) {
        // phase B: U1*h1(t-1). cnt1[t-1]==16 covers peers' h1(t-1) AND the ring
        // (slot t&7 free) -- checked before the h1 store below via this barrier.
        if (w == 0) pollc(cnt1, t - 1, lane);
        __syncthreads();
        l1_inv();
        gemm_slab(h1r + (size_t)((t - 1) & 7) * B_ * H_, kbase, l15, q, BfB, acc);
      }
#pragma unroll
      for (int mt = 0; mt < 4; ++mt)
#pragma unroll
        for (int nt = 0; nt < 4; ++nt)
#pragma unroll
          for (int r = 0; r < 4; ++r)
            red[w][mt * 16 + nt * 4 + r][lane ^ (r << 2)] = acc[mt][nt][r];
      __syncthreads();
      float vs[16];
#pragma unroll
      for (int ks = 0; ks < 4; ++ks)
#pragma unroll
        for (int ch = 0; ch < 4; ++ch) {
          f32x4 v = *(const f32x4*)&red[ks][iidx][lsb + ((ch << 2) ^ swz)];
          if (ks == 0) {
            vs[ch*4+0] = v[0]; vs[ch*4+1] = v[1]; vs[ch*4+2] = v[2]; vs[ch*4+3] = v[3];
          } else {
            vs[ch*4+0] += v[0]; vs[ch*4+1] += v[1]; vs[ch*4+2] += v[2]; vs[ch*4+3] += v[3];
          }
        }
      f16* hw = h1r + (size_t)(t & 7) * B_ * H_ + (size_t)bown * H_ + cbase;
      f16x8 o0, o1;
#pragma unroll
      for (int j = 0; j < 16; ++j) {
        float bs = (float)((j < 8) ? bsh[0][j] : bsh[1][j - 8]);
        float cf = (float)((j < 8) ? cfh[0][j] : cfh[1][j - 8]);
        float th = fast_tanh(vs[j] + bs);
        float h = hst[j];
        h = h + cf * (th - h);
        hst[j] = h;
        if (j < 8) o0[j] = (f16)h; else o1[j - 8] = (f16)h;
      }
      *(f16x8*)hw = o0;
      *(f16x8*)(hw + 8) = o1;
      if (t == 255) {
        float* op = out + (size_t)bown * H_ + cbase;
#pragma unroll
        for (int ch = 0; ch < 4; ++ch) {
          float4 vv;
          vv.x = hst[ch*4+0]; vv.y = hst[ch*4+1]; vv.z = hst[ch*4+2]; vv.w = hst[ch*4+3];
          *(float4*)(op + ch * 4) = vv;
        }
      }
      __syncthreads();  // vmcnt(0): h1 stores in L2 before publish
      if (tid == 0)
        __hip_atomic_fetch_add(cnt1 + t, 1, __ATOMIC_RELAXED, AGENT);
    }
  }
}

// Swizzle identity: writer lane L stores logical col L at physical col
// L ^ ((i&3)<<2). Reader (row iidx, iidx&3 == lane&3) reads physical
// lsb + ((ch<<2) ^ ((lane&3)<<2)) + nn, which un-XORs to logical
// lsb + ch*4 + nn. Writes are lane-permutations (conflict-free); b128 reads
// spread across all 32 banks (conflict-free).

extern "C" void kernel_launch(void* const* d_in, const int* in_sizes, int n_in,
                              void* d_out, int out_size, void* d_ws, size_t ws_size,
                              hipStream_t stream) {
  const float* x  = (const float*)d_in[0];
  const float* W0 = (const float*)d_in[1];
  const float* U0 = (const float*)d_in[2];
  const float* b0 = (const float*)d_in[3];
  const float* a0 = (const float*)d_in[4];
  const float* W1 = (const float*)d_in[5];
  const float* U1 = (const float*)d_in[6];
  const float* b1 = (const float*)d_in[7];
  const float* a1 = (const float*)d_in[8];
  char* ws = (char*)d_ws;
  f16*   wx  = (f16*)(ws + OFF_WX);
  f16*   h0r = (f16*)(ws + OFF_H0R);
  f16*   h1r = (f16*)(ws + OFF_H1R);
  int*   flg = (int*)(ws + OFF_FLG);
  float* out = (float*)d_out;

  hipMemsetAsync(flg, 0, 8192, stream);            // counters/election start at 0
  k_wx<<<512, 256, 0, stream>>>(x, W0, b0, wx);    // parallel Wx GEMM

  // 256 blocks: every XCD gets >=32 by pigeonhole; workers self-select onto one.
  k_persist<<<256, 256, 0, stream>>>(U0, W1, U1, a0, a1, b1, wx, h0r, h1r, flg, out);
}

// Round 6
// 2770.227 us; speedup vs baseline: 1.8885x; 1.0535x over previous
//
#include <hip/hip_runtime.h>

// Liquid NN: BATCH=64, SEQ=256, IN=512, HID=1024, 2 layers, tau=0.5.
// h0(t) = h0 + a0*2*(tanh(x_t@W0^T + b0 + h0@U0^T) - h0)
// h1(t) = h1 + a1*2*(tanh(h0(t)@W1^T + b1 + h1@U1^T) - h1)
// Output: h1(255) as f32 (64,1024).
//
// R10 = R9 (counter substrate, 2805->2650us profiled) minus the sync FABRIC:
// per-step arithmetic: ~256 MFMA/wave = 0.5us of compute vs 10.3us period ->
// 95% of the period was barriers/polls/invs/propagation, NOT slabs (why R7/R8
// slab-moving failed). This round strips fabric:
//  (1) PER-WAVE full-condition polls: every wave's lane0 (and lane1 for the
//      ring word) polls the single counter word itself -> the consumer-side
//      __syncthreads before each slab AND the wave0->others propagation are
//      gone. NO coverage gap (each wave checks the FULL 16-WG condition;
//      R5's bug was wave-local 4-word slices of a 16-word condition).
//      The post-store drain barrier stays (it also fences `red` reuse: reads
//      of step N's red finish before the barrier, next write is after it).
//  (2) NO l1_inv: between re-reads of the same ring address (8 steps apart)
//      each CU streams ~2MB (8 x 256KB slabs) through its 32KB L1 -> stale
//      lines are capacity-evicted with ~64x margin; vector stores are
//      write-through/no-allocate on CDNA. L2 (XCD coherence point) is always
//      fresh via the drain-barrier-then-publish protocol.
//      REVERT TRIGGER: absmax O(1) failure -> restore buffer_inv.
//  (3) k_wx grid 512->2048 (rt 8->2): more TLP on the serial prologue GEMM.
// Protocol (counters, depth-8 rings, UNCHANGED algebra):
//   role0 s: cnt0[s-1]==16 (peers' h0(s-1)), cnt1[s-8]==16 (slot s&7 consumed
//            by role1 AND role0 peers past s-7 implied by cnt0[s-1])
//   role1 t: phase A cnt0[t]==16 (h0(t) ready); phase B cnt1[t-1]==16
//            (peers' h1(t-1) ready + h1 ring slot t&7 free since t-1>=t-7)
//   publish: fetch_add(cnt[step]) by tid0 AFTER the vmcnt-drain barrier.
// R6 keepers: NT wx loads, fast exp-based tanh, XOR-swizzled LDS reduce,
// role1 single fused reduce (both slabs accumulate in regs).
// R8 lesson kept: 1 WG/CU, no launch_bounds occupancy cap (VGPR 256).

typedef _Float16 f16;
typedef _Float16 f16x8 __attribute__((ext_vector_type(8)));
typedef float    f32x4 __attribute__((ext_vector_type(4)));

#define B_  64
#define S_  256
#define IN_ 512
#define H_  1024

static constexpr size_t OFF_WX  = 0;         // S*B*H f16 = 33554432
static constexpr size_t OFF_H0R = 33554432;  // 8*B*H f16 = 1048576
static constexpr size_t OFF_H1R = 34603008;  // 8*B*H f16 = 1048576
static constexpr size_t OFF_FLG = 35651584;  // sync area (memset 8192 B)
// flg ints: cnt0[257]@0, cnt1[257]@512, ecnt[8]@1024, chosen@1032, ticket@1033

#define AGENT __HIP_MEMORY_SCOPE_AGENT

// ---------------- kernel: Wx = x @ W0^T + b0 (f32 in, f16 out) ----------------
__global__ __launch_bounds__(256) void k_wx(const float* __restrict__ x,
                                            const float* __restrict__ W0,
                                            const float* __restrict__ b0,
                                            f16* __restrict__ wx) {
  __shared__ uint4 xs[4096];  // 64 rows x 64 8-half chunks, chunk' = kc ^ (row&7)
  const int tid = threadIdx.x;
  const int w = tid >> 6, lane = tid & 63;
  const int q = lane >> 4, l15 = lane & 15;
  const int cslice = blockIdx.x & 15;
  const int rblock = blockIdx.x >> 4;  // 0..127
  const int c = cslice * 64 + w * 16 + l15;

  f16x8 Bf[16];  // B[k][n] = W0[c][k], lane holds k = kf*32 + q*8 + j
#pragma unroll
  for (int kf = 0; kf < 16; ++kf) {
    const float* p = W0 + (size_t)c * IN_ + kf * 32 + q * 8;
    f16x8 v;
#pragma unroll
    for (int j = 0; j < 8; ++j) v[j] = (f16)p[j];
    Bf[kf] = v;
  }
  const float bias = b0[c];

  for (int rt = 0; rt < 2; ++rt) {
    const int row0 = rblock * 128 + rt * 64;
    __syncthreads();
#pragma unroll
    for (int it = 0; it < 16; ++it) {
      int g = it * 256 + tid;
      int r = g >> 6, kc = g & 63;
      const float* xp = x + (size_t)(row0 + r) * IN_ + kc * 8;
      float4 v0 = *(const float4*)xp;
      float4 v1 = *(const float4*)(xp + 4);
      f16x8 h;
      h[0] = (f16)v0.x; h[1] = (f16)v0.y; h[2] = (f16)v0.z; h[3] = (f16)v0.w;
      h[4] = (f16)v1.x; h[5] = (f16)v1.y; h[6] = (f16)v1.z; h[7] = (f16)v1.w;
      xs[r * 64 + (kc ^ (r & 7))] = *(uint4*)&h;
    }
    __syncthreads();
    f32x4 acc[4] = {};
#pragma unroll
    for (int mt = 0; mt < 4; ++mt) {
      const int r = mt * 16 + l15;
#pragma unroll
      for (int kf = 0; kf < 16; ++kf) {
        uint4 av = xs[r * 64 + ((kf * 4 + q) ^ (r & 7))];
        f16x8 a = *(f16x8*)&av;
        acc[mt] = __builtin_amdgcn_mfma_f32_16x16x32_f16(a, Bf[kf], acc[mt], 0, 0, 0);
      }
    }
#pragma unroll
    for (int mt = 0; mt < 4; ++mt) {
#pragma unroll
      for (int r = 0; r < 4; ++r) {
        int rowg = row0 + mt * 16 + q * 4 + r;  // = b*256 + t
        int b = rowg >> 8, t = rowg & 255;
        wx[((size_t)t * B_ + b) * H_ + c] = (f16)(acc[mt][r] + bias);
      }
    }
  }
}

// ---------------- persistent recurrent kernel ----------------
// counter poll, per-wave: lane 0 waits cnt[idx] >= 16. ONE word, ONE tx per
// check, s_sleep(4) backoff after the first (hot) check. idx<0 -> no-op.
__device__ __forceinline__ void pollc(const int* cn, int idx, int lane) {
  if (idx < 0) return;
  const int* p = cn + idx;
  bool pend = (lane == 0);
  if (pend && __hip_atomic_load((int*)p, __ATOMIC_RELAXED, AGENT) >= 16)
    pend = false;
  while (__ballot(pend)) {
    __builtin_amdgcn_s_sleep(4);
    if (pend && __hip_atomic_load((int*)p, __ATOMIC_RELAXED, AGENT) >= 16)
      pend = false;
  }
}

// dual poll, per-wave: lane 0 waits a[ia]>=16, lane 1 waits b[ib]>=16.
__device__ __forceinline__ void pollc2(const int* a, int ia,
                                       const int* b, int ib, int lane) {
  const bool la = (lane == 0) && (ia >= 0);
  const bool lb = (lane == 1) && (ib >= 0);
  const int* p = la ? (a + ia) : (b + (ib < 0 ? 0 : ib));
  bool pend = la || lb;
  if (pend && __hip_atomic_load((int*)p, __ATOMIC_RELAXED, AGENT) >= 16)
    pend = false;
  while (__ballot(pend)) {
    __builtin_amdgcn_s_sleep(4);
    if (pend && __hip_atomic_load((int*)p, __ATOMIC_RELAXED, AGENT) >= 16)
      pend = false;
  }
}

// fast tanh: t = e^{-2|x|} in (0,1], tanh = sign(x)*(1-t)/(1+t). ~1e-7 abs err.
__device__ __forceinline__ float fast_tanh(float x) {
  float t = __expf(-2.0f * fabsf(x));
  float r = (1.0f - t) / (1.0f + t);
  return copysignf(r, x);
}

// one wave: 64-batch x 64-col x 256-K slab, software-pipelined A loads.
__device__ __forceinline__ void gemm_slab(const f16* __restrict__ A, int kbase,
                                          int l15, int q,
                                          const f16x8 (&Bf)[4][8], f32x4 (&acc)[4][4]) {
  f16x8 cur[8], nxt[8];
  const f16* ar0 = A + (size_t)l15 * H_ + kbase + q * 8;
#pragma unroll
  for (int kf = 0; kf < 8; ++kf) cur[kf] = *(const f16x8*)(ar0 + kf * 32);
#pragma unroll
  for (int mt = 0; mt < 4; ++mt) {
    if (mt < 3) {
      const f16* ar = A + (size_t)((mt + 1) * 16 + l15) * H_ + kbase + q * 8;
#pragma unroll
      for (int kf = 0; kf < 8; ++kf) nxt[kf] = *(const f16x8*)(ar + kf * 32);
    }
#pragma unroll
    for (int nt = 0; nt < 4; ++nt)
#pragma unroll
      for (int kf = 0; kf < 8; ++kf)
        acc[mt][nt] = __builtin_amdgcn_mfma_f32_16x16x32_f16(cur[kf], Bf[nt][kf],
                                                             acc[mt][nt], 0, 0, 0);
#pragma unroll
    for (int kf = 0; kf < 8; ++kf) cur[kf] = nxt[kf];
  }
}

__global__ __launch_bounds__(256, 1) void k_persist(
    const float* __restrict__ U0, const float* __restrict__ W1,
    const float* __restrict__ U1, const float* __restrict__ alpha0,
    const float* __restrict__ alpha1, const float* __restrict__ b1,
    const f16* __restrict__ wx, f16* h0r, f16* h1r, int* flg, float* out) {
  // red[ks][i][col]: D[m][n] of K-slice ks, m=(i>>4)*16+(col>>4)*4+(i&3),
  // n=((i>>2)&3)*16+(col&15), stored XOR-swizzled at col' = col ^ ((i&3)<<2).
  // aligned(16): epilogue does b128 LDS reads (under-aligned b128 = fault).
  __shared__ __attribute__((aligned(16))) float red[4][64][64];  // exactly 64 KiB
  const int tid = threadIdx.x;
  const int w = tid >> 6, lane = tid & 63;
  const int q = lane >> 4, l15 = lane & 15;

  int* cnt0   = flg;         // cnt0[s] = #role0 WGs that finished step s
  int* cnt1   = flg + 512;   // cnt1[t] = #role1 WGs that finished step t
  int* ecnt   = flg + 1024;
  int* chosen = flg + 1032;
  int* ticket = flg + 1033;

  // ---- elect one XCD; 32 workers there; everyone else exits (R4-validated) ----
  const int xcc = (int)__builtin_amdgcn_s_getreg(6164) & 7;  // HW_REG_XCC_ID
  int* sh = (int*)&red[0][0][0];
  if (tid == 0) {
    __hip_atomic_fetch_add(ecnt + xcc, 1, __ATOMIC_RELAXED, AGENT);
    if (blockIdx.x == 0) {
      int sel = -1;
      while (sel < 0) {
        for (int i = 0; i < 8; ++i)
          if (__hip_atomic_load(ecnt + i, __ATOMIC_RELAXED, AGENT) >= 32) { sel = i; break; }
        if (sel < 0) __builtin_amdgcn_s_sleep(1);
      }
      __hip_atomic_fetch_add(chosen, sel + 1, __ATOMIC_RELAXED, AGENT);
    }
    int ch;
    while ((ch = __hip_atomic_load(chosen, __ATOMIC_RELAXED, AGENT)) == 0)
      __builtin_amdgcn_s_sleep(1);
    int my = -1;
    if (xcc == ch - 1) my = __hip_atomic_fetch_add(ticket, 1, __ATOMIC_RELAXED, AGENT);
    sh[0] = my;
  }
  __syncthreads();
  const int myid = sh[0];
  __syncthreads();
  if (myid < 0 || myid >= 32) return;
  const int role = myid >> 4, slice = myid & 15;
  const int c0 = slice * 64;
  const int kbase = w * 256;

  // ---- weight slices into registers: B[k][n] = Wm[c][k] ----
  f16x8 BfA[4][8];  // role0: U0 ; role1: W1
  f16x8 BfB[4][8];  // role1: U1
  {
    const float* WmA = (role == 0) ? U0 : W1;
#pragma unroll
    for (int nt = 0; nt < 4; ++nt)
#pragma unroll
      for (int kf = 0; kf < 8; ++kf) {
        const float* p = WmA + (size_t)(c0 + nt * 16 + l15) * H_ + kbase + kf * 32 + q * 8;
        f16x8 v;
#pragma unroll
        for (int j = 0; j < 8; ++j) v[j] = (f16)p[j];
        BfA[nt][kf] = v;
      }
    if (role == 1) {
#pragma unroll
      for (int nt = 0; nt < 4; ++nt)
#pragma unroll
        for (int kf = 0; kf < 8; ++kf) {
          const float* p = U1 + (size_t)(c0 + nt * 16 + l15) * H_ + kbase + kf * 32 + q * 8;
          f16x8 v;
#pragma unroll
          for (int j = 0; j < 8; ++j) v[j] = (f16)p[j];
          BfB[nt][kf] = v;
        }
    }
  }

  // ---- epilogue ownership: thread owns batch row bown, cols cbase..cbase+15 ----
  const int bown = w * 16 + (lane & 15);
  const int gq   = lane >> 4;
  const int iidx = w * 16 + gq * 4 + (lane & 3);  // fixed LDS row
  const int lsb  = ((lane >> 2) & 3) * 16;        // fixed logical col base
  const int swz  = (lane & 3) << 2;               // read-side XOR (row&3 == lane&3)
  const int cbase = c0 + gq * 16;

  f16x8 cfh[2], bsh[2];  // packed alpha*2 and bias for the 16 owned cols
  {
    const float* ap = ((role == 0) ? alpha0 : alpha1) + cbase;
    const float* bp = b1 + cbase;
    f16x8 t0, t1, u0, u1;
#pragma unroll
    for (int j = 0; j < 8; ++j) {
      t0[j] = (f16)(ap[j] * 2.0f);
      t1[j] = (f16)(ap[8 + j] * 2.0f);
      u0[j] = (f16)bp[j];
      u1[j] = (f16)bp[8 + j];
    }
    cfh[0] = t0; cfh[1] = t1; bsh[0] = u0; bsh[1] = u1;
  }

  float hst[16];
#pragma unroll
  for (int i = 0; i < 16; ++i) hst[i] = 0.f;

  if (role == 0) {
    for (int s = 0; s < 256; ++s) {
      // prefetch wx[s] for owned (b, cols): 2 x b128 NT loads (no L2 allocate ->
      // h-rings stay L2-resident), in flight during the poll
      const f16* wp = wx + ((size_t)s * B_ + bown) * H_ + cbase;
      f16x8 wxa = __builtin_nontemporal_load((const f16x8*)wp);
      f16x8 wxb = __builtin_nontemporal_load((const f16x8*)(wp + 8));
      f32x4 acc[4][4] = {};
      if (s > 0) {
        // every wave checks BOTH full conditions itself -> no barrier needed.
        pollc2(cnt0, s - 1, cnt1, s - 8, lane);
        gemm_slab(h0r + (size_t)((s - 1) & 7) * B_ * H_, kbase, l15, q, BfA, acc);
      }
#pragma unroll
      for (int mt = 0; mt < 4; ++mt)
#pragma unroll
        for (int nt = 0; nt < 4; ++nt)
#pragma unroll
          for (int r = 0; r < 4; ++r)
            red[w][mt * 16 + nt * 4 + r][lane ^ (r << 2)] = acc[mt][nt][r];
      __syncthreads();
      float vs[16];
#pragma unroll
      for (int ks = 0; ks < 4; ++ks)
#pragma unroll
        for (int ch = 0; ch < 4; ++ch) {
          f32x4 v = *(const f32x4*)&red[ks][iidx][lsb + ((ch << 2) ^ swz)];
          if (ks == 0) {
            vs[ch*4+0] = v[0]; vs[ch*4+1] = v[1]; vs[ch*4+2] = v[2]; vs[ch*4+3] = v[3];
          } else {
            vs[ch*4+0] += v[0]; vs[ch*4+1] += v[1]; vs[ch*4+2] += v[2]; vs[ch*4+3] += v[3];
          }
        }
      f16* hw = h0r + (size_t)(s & 7) * B_ * H_ + (size_t)bown * H_ + cbase;
      f16x8 o0, o1;
#pragma unroll
      for (int j = 0; j < 16; ++j) {
        float wxv = (float)((j < 8) ? wxa[j] : wxb[j - 8]);
        float cf  = (float)((j < 8) ? cfh[0][j] : cfh[1][j - 8]);
        float th = fast_tanh(vs[j] + wxv);
        float h = hst[j];
        h = h + cf * (th - h);
        hst[j] = h;
        if (j < 8) o0[j] = (f16)h; else o1[j - 8] = (f16)h;
      }
      *(f16x8*)hw = o0;
      *(f16x8*)(hw + 8) = o1;
      // drain barrier: all waves' h stores at L2 before publish; ALSO fences
      // red reuse (all reduce-reads of this step precede it).
      __syncthreads();
      if (tid == 0)
        __hip_atomic_fetch_add(cnt0 + s, 1, __ATOMIC_RELAXED, AGENT);
    }
  } else {
    for (int t = 0; t < 256; ++t) {
      f32x4 acc[4][4] = {};
      // phase A: W1*h0(t) -- dep satisfied ~8 steps early (ring slack), so the
      // per-wave poll is a single hot load; no barrier, straight into the slab.
      pollc(cnt0, t, lane);
      gemm_slab(h0r + (size_t)(t & 7) * B_ * H_, kbase, l15, q, BfA, acc);
      if (t > 0) {
        // phase B: U1*h1(t-1); cnt1[t-1]==16 covers peers' h1(t-1) AND the h1
        // ring slot (t-1 >= t-7). Per-wave poll, no barrier.
        pollc(cnt1, t - 1, lane);
        gemm_slab(h1r + (size_t)((t - 1) & 7) * B_ * H_, kbase, l15, q, BfB, acc);
      }
#pragma unroll
      for (int mt = 0; mt < 4; ++mt)
#pragma unroll
        for (int nt = 0; nt < 4; ++nt)
#pragma unroll
          for (int r = 0; r < 4; ++r)
            red[w][mt * 16 + nt * 4 + r][lane ^ (r << 2)] = acc[mt][nt][r];
      __syncthreads();
      float vs[16];
#pragma unroll
      for (int ks = 0; ks < 4; ++ks)
#pragma unroll
        for (int ch = 0; ch < 4; ++ch) {
          f32x4 v = *(const f32x4*)&red[ks][iidx][lsb + ((ch << 2) ^ swz)];
          if (ks == 0) {
            vs[ch*4+0] = v[0]; vs[ch*4+1] = v[1]; vs[ch*4+2] = v[2]; vs[ch*4+3] = v[3];
          } else {
            vs[ch*4+0] += v[0]; vs[ch*4+1] += v[1]; vs[ch*4+2] += v[2]; vs[ch*4+3] += v[3];
          }
        }
      f16* hw = h1r + (size_t)(t & 7) * B_ * H_ + (size_t)bown * H_ + cbase;
      f16x8 o0, o1;
#pragma unroll
      for (int j = 0; j < 16; ++j) {
        float bs = (float)((j < 8) ? bsh[0][j] : bsh[1][j - 8]);
        float cf = (float)((j < 8) ? cfh[0][j] : cfh[1][j - 8]);
        float th = fast_tanh(vs[j] + bs);
        float h = hst[j];
        h = h + cf * (th - h);
        hst[j] = h;
        if (j < 8) o0[j] = (f16)h; else o1[j - 8] = (f16)h;
      }
      *(f16x8*)hw = o0;
      *(f16x8*)(hw + 8) = o1;
      if (t == 255) {
        float* op = out + (size_t)bown * H_ + cbase;
#pragma unroll
        for (int ch = 0; ch < 4; ++ch) {
          float4 vv;
          vv.x = hst[ch*4+0]; vv.y = hst[ch*4+1]; vv.z = hst[ch*4+2]; vv.w = hst[ch*4+3];
          *(float4*)(op + ch * 4) = vv;
        }
      }
      __syncthreads();  // drain h1 stores + fence red reuse
      if (tid == 0)
        __hip_atomic_fetch_add(cnt1 + t, 1, __ATOMIC_RELAXED, AGENT);
    }
  }
}

// Swizzle identity: writer lane L stores logical col L at physical col
// L ^ ((i&3)<<2). Reader (row iidx, iidx&3 == lane&3) reads physical
// lsb + ((ch<<2) ^ ((lane&3)<<2)) + nn, which un-XORs to logical
// lsb + ch*4 + nn. Writes are lane-permutations (conflict-free); b128 reads
// spread across all 32 banks (conflict-free).

extern "C" void kernel_launch(void* const* d_in, const int* in_sizes, int n_in,
                              void* d_out, int out_size, void* d_ws, size_t ws_size,
                              hipStream_t stream) {
  const float* x  = (const float*)d_in[0];
  const float* W0 = (const float*)d_in[1];
  const float* U0 = (const float*)d_in[2];
  const float* b0 = (const float*)d_in[3];
  const float* a0 = (const float*)d_in[4];
  const float* W1 = (const float*)d_in[5];
  const float* U1 = (const float*)d_in[6];
  const float* b1 = (const float*)d_in[7];
  const float* a1 = (const float*)d_in[8];
  char* ws = (char*)d_ws;
  f16*   wx  = (f16*)(ws + OFF_WX);
  f16*   h0r = (f16*)(ws + OFF_H0R);
  f16*   h1r = (f16*)(ws + OFF_H1R);
  int*   flg = (int*)(ws + OFF_FLG);
  float* out = (float*)d_out;

  hipMemsetAsync(flg, 0, 8192, stream);            // counters/election start at 0
  k_wx<<<2048, 256, 0, stream>>>(x, W0, b0, wx);   // parallel Wx GEMM (more TLP)

  // 256 blocks: every XCD gets >=32 by pigeonhole; workers self-select onto one.
  k_persist<<<256, 256, 0, stream>>>(U0, W1, U1, a0, a1, b1, wx, h0r, h1r, flg, out);
}